// Round 10
// baseline (178.369 us; speedup 1.0000x reference)
//
#include <hip/hip_runtime.h>
#include <hip/hip_bf16.h>
#include <math.h>

typedef __attribute__((ext_vector_type(8))) __bf16 bf16x8;
typedef __attribute__((ext_vector_type(4))) float f32x4;

#define HEADS 12
#define DHEAD 64
#define NTOK 2049
#define BATCH 2
#define DIM 768
#define QKV3 2304
#define MROWS 4098   // BATCH*NTOK
#define MP 4224      // padded to 33*128 (and 66*64)
#define ATT_SCALE 0.125f
#define BKS 64
#define NSPLIT 33    // 33 chunks of 64 keys cover 2049
#define PSTRIDE 68   // floats per (b,h,split) partial record: o[64], m, l, pad

#define CVT_BLOCKS 1584
#define TQKV_BX 72
#define TQKV_BLOCKS (72 * 24)
#define TOUT_BX 24
#define TOUT_BLOCKS (24 * 24)
#define PREP_BLOCKS (CVT_BLOCKS + TQKV_BLOCKS + TOUT_BLOCKS)
#define WIN_BLOCKS (BATCH * 129 * 3)   // 774

// Bijective XCD chunk swizzle (m204): hardware block o -> work id, so that the
// 8-way round-robin XCD dispatch gives each XCD a CONTIGUOUS chunk of work ids.
__device__ __forceinline__ int xcd_swz(int o, int nwg) {
  const int q = nwg >> 3, r = nwg & 7;
  const int xcd = o & 7, i = o >> 3;
  return (xcd < r ? xcd * (q + 1) : r * (q + 1) + (xcd - r) * q) + i;
}

// ---------------- fused prep: cvt_x + transpose w_qkv + transpose w_out ----------------
__global__ __launch_bounds__(256) void prep_kernel(const float* __restrict__ x,
                                                   const float* __restrict__ w_qkv,
                                                   const float* __restrict__ w_out,
                                                   __bf16* __restrict__ xb,
                                                   __bf16* __restrict__ wqkvT,
                                                   __bf16* __restrict__ woutT,
                                                   int* __restrict__ cnt) {
  __shared__ float tile[32][33];
  const int b = blockIdx.x, tid = threadIdx.x;
  if (b == 0 && tid < BATCH * HEADS) cnt[tid] = 0;  // zero CLS completion counters
  if (b < CVT_BLOCKS) {
    long e = ((long)b * 256 + tid) * 8;   // 8 elems/thread, 768%8==0 keeps in-row
    int row = (int)(e / DIM);
    bf16x8 v;
    if (row < MROWS) {
      const float4 a = *(const float4*)(x + e);
      const float4 c = *(const float4*)(x + e + 4);
      v[0] = (__bf16)a.x; v[1] = (__bf16)a.y; v[2] = (__bf16)a.z; v[3] = (__bf16)a.w;
      v[4] = (__bf16)c.x; v[5] = (__bf16)c.y; v[6] = (__bf16)c.z; v[7] = (__bf16)c.w;
    } else {
#pragma unroll
      for (int j = 0; j < 8; ++j) v[j] = (__bf16)0.f;
    }
    *(bf16x8*)(xb + e) = v;
    return;
  }
  const float* in;
  __bf16* outp;
  int C, bx, by;
  if (b < CVT_BLOCKS + TQKV_BLOCKS) {
    int idx = b - CVT_BLOCKS;
    bx = idx % TQKV_BX; by = idx / TQKV_BX;
    in = w_qkv; outp = wqkvT; C = QKV3;
  } else {
    int idx = b - CVT_BLOCKS - TQKV_BLOCKS;
    bx = idx % TOUT_BX; by = idx / TOUT_BX;
    in = w_out; outp = woutT; C = DIM;
  }
  const int R = DIM;
  const int c0 = bx * 32, r0 = by * 32;
  const int tx = tid & 31, ty = tid >> 5;
#pragma unroll
  for (int i = 0; i < 4; ++i) {
    int r = ty + i * 8;
    tile[r][tx] = in[(size_t)(r0 + r) * C + c0 + tx];
  }
  __syncthreads();
#pragma unroll
  for (int i = 0; i < 4; ++i) {
    int r = ty + i * 8;
    outp[(size_t)(c0 + r) * R + r0 + tx] = (__bf16)tile[tx][r];
  }
}

// ---------------- qkv GEMM: C[M][2304] = xb[M][768] * wqkvT[2304][768]^T ----------------
// 64x128 tile, 1D grid 1188 with XCD m-band swizzle, 4 waves 2x2, BK=64,
// dbuf + prefetch-first, T2 swizzle via inverse-swizzled global source col.
__global__ __launch_bounds__(256) void gemm_qkv_kernel(const __bf16* __restrict__ A,
                                                       const __bf16* __restrict__ Bt,
                                                       __bf16* __restrict__ C) {
  __shared__ __bf16 sA[2][64 * BKS];
  __shared__ __bf16 sB[2][128 * BKS];
  const int wg = xcd_swz(blockIdx.x, (MP / 64) * (QKV3 / 128));  // by-major: chunk = A-band
  const int by = wg / (QKV3 / 128), bx = wg % (QKV3 / 128);
  const int tid = threadIdx.x;
  const int w = tid >> 6, lane = tid & 63;
  const int m0 = by * 64, n0 = bx * 128;
  const int wr = w >> 1, wc = w & 1;
  const int K = DIM;
  f32x4 acc[2][4] = {};

  const int srow = (w << 3) + (lane >> 3);                 // 0..31; +it*32 keeps row&7
  const int scolE = ((lane & 7) ^ (lane >> 3)) << 3;       // inverse-swizzled source col
  const __bf16* gA = A + (size_t)(m0 + srow) * K + scolE;
  const __bf16* gB = Bt + (size_t)(n0 + srow) * K + scolE;
  const int nk = K / BKS;  // 12

#define STAGE_Q(buf, kt)                                                                 \
  do {                                                                                   \
    _Pragma("unroll")                                                                    \
    for (int it = 0; it < 2; ++it) {                                                     \
      __builtin_amdgcn_global_load_lds(                                                  \
          (const __attribute__((address_space(1))) void*)(gA + (size_t)(it * 32) * K + (kt)), \
          (__attribute__((address_space(3))) void*)(&sA[buf][(it << 11) + (w << 9)]), 16, 0, 0); \
    }                                                                                    \
    _Pragma("unroll")                                                                    \
    for (int it = 0; it < 4; ++it) {                                                     \
      __builtin_amdgcn_global_load_lds(                                                  \
          (const __attribute__((address_space(1))) void*)(gB + (size_t)(it * 32) * K + (kt)), \
          (__attribute__((address_space(3))) void*)(&sB[buf][(it << 11) + (w << 9)]), 16, 0, 0); \
    }                                                                                    \
  } while (0)

  STAGE_Q(0, 0);
  __syncthreads();

  const int sw0 = ((lane >> 4) ^ (lane & 7)) << 3;   // kk=0 swizzled slot
  const int sw1 = sw0 ^ 32;                          // kk=32
  const int rofA = (wr * 32 + (lane & 15)) * BKS;
  const int rofB = (wc * 64 + (lane & 15)) * BKS;

  for (int t = 0; t < nk; ++t) {
    const int cur = t & 1;
    if (t + 1 < nk) STAGE_Q(cur ^ 1, (t + 1) * BKS);  // issue next-tile loads first
    const __bf16* bufA = sA[cur];
    const __bf16* bufB = sB[cur];
#pragma unroll
    for (int kk = 0; kk < BKS; kk += 32) {
      const int so = (kk == 0) ? sw0 : sw1;
      bf16x8 af[2], bfr[4];
#pragma unroll
      for (int m = 0; m < 2; ++m)
        af[m] = *(const bf16x8*)&bufA[rofA + m * 16 * BKS + so];
#pragma unroll
      for (int n = 0; n < 4; ++n)
        bfr[n] = *(const bf16x8*)&bufB[rofB + n * 16 * BKS + so];
#pragma unroll
      for (int m = 0; m < 2; ++m)
#pragma unroll
        for (int n = 0; n < 4; ++n)
          acc[m][n] = __builtin_amdgcn_mfma_f32_16x16x32_bf16(af[m], bfr[n], acc[m][n], 0, 0, 0);
    }
    __syncthreads();
  }
#undef STAGE_Q

#pragma unroll
  for (int m = 0; m < 2; ++m) {
#pragma unroll
    for (int n = 0; n < 4; ++n) {
      int col = n0 + wc * 64 + n * 16 + (lane & 15);
      int rbase = m0 + wr * 32 + m * 16 + ((lane >> 4) << 2);
#pragma unroll
      for (int r = 0; r < 4; ++r) {
        C[(size_t)(rbase + r) * QKV3 + col] = (__bf16)acc[m][n][r];
      }
    }
  }
}

// ---------------- out GEMM: out[M][768] = attnb[M][768]*woutT[768][768]^T + bias ----------------
// 64x64 tile, 1D grid 792 with XCD m-band swizzle, 4 waves 2x2, BK=64, dbuf, swizzle.
__global__ __launch_bounds__(256) void gemm_out_kernel(const __bf16* __restrict__ A,
                                                       const __bf16* __restrict__ Bt,
                                                       float* __restrict__ Cv,
                                                       const float* __restrict__ bias) {
  __shared__ __bf16 sA[2][64 * BKS];
  __shared__ __bf16 sB[2][64 * BKS];
  const int wg = xcd_swz(blockIdx.x, (MP / 64) * (DIM / 64));
  const int by = wg / (DIM / 64), bx = wg % (DIM / 64);
  const int tid = threadIdx.x;
  const int w = tid >> 6, lane = tid & 63;
  const int m0 = by * 64, n0 = bx * 64;
  const int wr = w >> 1, wc = w & 1;
  const int K = DIM, N = DIM;
  f32x4 acc[2][2] = {};

  const int srow = (w << 3) + (lane >> 3);
  const int scol = ((lane & 7) ^ (lane >> 3)) << 3;
  const __bf16* gA = A + (size_t)(m0 + srow) * K + scol;
  const __bf16* gB = Bt + (size_t)(n0 + srow) * K + scol;
  const int nk = K / BKS;

#define STAGE_O(buf, kt)                                                                 \
  do {                                                                                   \
    _Pragma("unroll")                                                                    \
    for (int it = 0; it < 2; ++it) {                                                     \
      __builtin_amdgcn_global_load_lds(                                                  \
          (const __attribute__((address_space(1))) void*)(gA + (size_t)(it * 32) * K + (kt)), \
          (__attribute__((address_space(3))) void*)(&sA[buf][(it << 11) + (w << 9)]), 16, 0, 0); \
      __builtin_amdgcn_global_load_lds(                                                  \
          (const __attribute__((address_space(1))) void*)(gB + (size_t)(it * 32) * K + (kt)), \
          (__attribute__((address_space(3))) void*)(&sB[buf][(it << 11) + (w << 9)]), 16, 0, 0); \
    }                                                                                    \
  } while (0)

  STAGE_O(0, 0);
  __syncthreads();

  const int sw0 = ((lane >> 4) ^ (lane & 7)) << 3;
  const int sw1 = sw0 ^ 32;
  const int rofA = (wr * 32 + (lane & 15)) * BKS;
  const int rofB = (wc * 32 + (lane & 15)) * BKS;

  for (int t = 0; t < nk; ++t) {
    const int cur = t & 1;
    if (t + 1 < nk) STAGE_O(cur ^ 1, (t + 1) * BKS);
    const __bf16* bufA = sA[cur];
    const __bf16* bufB = sB[cur];
#pragma unroll
    for (int kk = 0; kk < BKS; kk += 32) {
      const int so = (kk == 0) ? sw0 : sw1;
      bf16x8 af[2], bfr[2];
#pragma unroll
      for (int m = 0; m < 2; ++m)
        af[m] = *(const bf16x8*)&bufA[rofA + m * 16 * BKS + so];
#pragma unroll
      for (int n = 0; n < 2; ++n)
        bfr[n] = *(const bf16x8*)&bufB[rofB + n * 16 * BKS + so];
#pragma unroll
      for (int m = 0; m < 2; ++m)
#pragma unroll
        for (int n = 0; n < 2; ++n)
          acc[m][n] = __builtin_amdgcn_mfma_f32_16x16x32_bf16(af[m], bfr[n], acc[m][n], 0, 0, 0);
    }
    __syncthreads();
  }
#undef STAGE_O

#pragma unroll
  for (int m = 0; m < 2; ++m) {
#pragma unroll
    for (int n = 0; n < 2; ++n) {
      int col = n0 + wc * 32 + n * 16 + (lane & 15);
      int rbase = m0 + wr * 32 + m * 16 + ((lane >> 4) << 2);
#pragma unroll
      for (int r = 0; r < 4; ++r) {
        int row = rbase + r;
        if (row < MROWS) Cv[(size_t)row * N + col] = acc[m][n][r] + bias[col];
      }
    }
  }
}

// ---------------- fused attention: windows (t>=1, two-pass, global loads) ----------------
// + CLS split-K partials with last-block-done fused reduction.
__global__ __launch_bounds__(64) void attn_fused_kernel(const __bf16* __restrict__ qkv,
                                                        __bf16* __restrict__ attnb,
                                                        float* __restrict__ part,
                                                        int* __restrict__ cnt) {
  __shared__ float sp_lds[64];
  const int lane = threadIdx.x;

  if (blockIdx.x < WIN_BLOCKS) {
    int bidx = blockIdx.x;
    int hg = bidx % 3; bidx /= 3;
    int blk = bidx % 129;
    int bb = bidx / 129;
    int h = hg * 4 + (lane >> 4);
    int qi = lane & 15;
    int t0 = (blk == 0) ? 1 : 2 + 16 * (blk - 1);
    int nt = (blk == 0) ? 1 : ((NTOK - t0) < 16 ? (NTOK - t0) : 16);
    bool active = qi < nt;
    int qt = t0 + (active ? qi : nt - 1);
    const size_t base = (size_t)bb * NTOK * QKV3;

    float q[64];
    {
      const __bf16* qp = qkv + base + (size_t)qt * QKV3 + h * DHEAD;
#pragma unroll
      for (int d0 = 0; d0 < 64; d0 += 8) {
        bf16x8 v = *(const bf16x8*)(qp + d0);
#pragma unroll
        for (int j = 0; j < 8; ++j) q[d0 + j] = (float)v[j];
      }
    }

    float s[17];
    float mx = -3.4e38f;
#pragma unroll
    for (int j = 0; j < 17; ++j) {
      int jc = (j - 1) < (nt - 1) ? (j - 1) : (nt - 1);
      int kt = (j == 0) ? 0 : t0 + jc;
      const __bf16* kp = qkv + base + (size_t)kt * QKV3 + DIM + h * DHEAD;
      float dot = 0.f;
#pragma unroll
      for (int d0 = 0; d0 < 64; d0 += 8) {
        bf16x8 v = *(const bf16x8*)(kp + d0);
#pragma unroll
        for (int jj = 0; jj < 8; ++jj) dot = fmaf(q[d0 + jj], (float)v[jj], dot);
      }
      s[j] = (j <= nt) ? dot * ATT_SCALE : -3.4e38f;
      mx = fmaxf(mx, s[j]);
    }
    float sum = 0.f;
#pragma unroll
    for (int j = 0; j < 17; ++j) {
      s[j] = expf(s[j] - mx);
      sum += s[j];
    }
    float inv = 1.f / sum;

    float o[64];
#pragma unroll
    for (int d = 0; d < 64; ++d) o[d] = 0.f;
#pragma unroll
    for (int j = 0; j < 17; ++j) {
      int jc = (j - 1) < (nt - 1) ? (j - 1) : (nt - 1);
      int vt = (j == 0) ? 0 : t0 + jc;
      const __bf16* vp = qkv + base + (size_t)vt * QKV3 + 2 * DIM + h * DHEAD;
      float p = s[j];
#pragma unroll
      for (int d0 = 0; d0 < 64; d0 += 8) {
        bf16x8 v = *(const bf16x8*)(vp + d0);
#pragma unroll
        for (int jj = 0; jj < 8; ++jj) o[d0 + jj] = fmaf(p, (float)v[jj], o[d0 + jj]);
      }
    }

    if (active) {
      __bf16* op = attnb + (size_t)(bb * NTOK + qt) * DIM + h * DHEAD;
#pragma unroll
      for (int d0 = 0; d0 < 64; d0 += 8) {
        bf16x8 v;
#pragma unroll
        for (int j = 0; j < 8; ++j) v[j] = (__bf16)(o[d0 + j] * inv);
        *(bf16x8*)(op + d0) = v;
      }
    }
    return;
  }

  // ---- CLS split-K partials: 1 wave per (b, h, 64-key chunk) ----
  int bid = blockIdx.x - WIN_BLOCKS;
  const int sp = bid % NSPLIT;
  const int bh = bid / NSPLIT;
  const int h = bh % HEADS;
  const int bb = bh / HEADS;
  const size_t base = (size_t)bb * NTOK * QKV3;

  float q[64];
  {
    const __bf16* qp = qkv + base + h * DHEAD;
#pragma unroll
    for (int d0 = 0; d0 < 64; d0 += 8) {
      bf16x8 v = *(const bf16x8*)(qp + d0);
#pragma unroll
      for (int j = 0; j < 8; ++j) q[d0 + j] = (float)v[j];
    }
  }

  const int t = sp * 64 + lane;
  const bool valid = t < NTOK;
  const int tc = valid ? t : NTOK - 1;
  float dot = 0.f;
  {
    const __bf16* kp = qkv + base + (size_t)tc * QKV3 + DIM + h * DHEAD;
#pragma unroll
    for (int d0 = 0; d0 < 64; d0 += 8) {
      bf16x8 v = *(const bf16x8*)(kp + d0);
#pragma unroll
      for (int j = 0; j < 8; ++j) dot = fmaf(q[d0 + j], (float)v[j], dot);
    }
  }
  float s = valid ? dot * ATT_SCALE : -3.4e38f;

  float m = s;
#pragma unroll
  for (int off = 32; off > 0; off >>= 1) m = fmaxf(m, __shfl_xor(m, off, 64));
  float p = valid ? expf(s - m) : 0.f;
  float l = p;
#pragma unroll
  for (int off = 32; off > 0; off >>= 1) l += __shfl_xor(l, off, 64);

  sp_lds[lane] = p;
  __syncthreads();

  const int nt = (NTOK - sp * 64) < 64 ? (NTOK - sp * 64) : 64;
  float o = 0.f;
  const __bf16* vcol = qkv + base + (size_t)(sp * 64) * QKV3 + 2 * DIM + h * DHEAD + lane;
  for (int tt = 0; tt < nt; ++tt) {
    o = fmaf(sp_lds[tt], (float)vcol[(size_t)tt * QKV3], o);
  }

  float* pb = part + ((size_t)bh * NSPLIT + sp) * PSTRIDE;
  pb[lane] = o;
  if (lane == 0) { pb[64] = m; pb[65] = l; }

  // ---- last-block-done: the 33rd finisher for this (b,h) does the reduction ----
  __threadfence();
  int last = 0;
  if (lane == 0) last = (atomicAdd(&cnt[bh], 1) == NSPLIT - 1) ? 1 : 0;
  last = __shfl(last, 0, 64);
  if (!last) return;
  __threadfence();

  const float* pb0 = part + (size_t)bh * NSPLIT * PSTRIDE;
  float M = -3.4e38f;
#pragma unroll
  for (int i = 0; i < NSPLIT; ++i) M = fmaxf(M, pb0[i * PSTRIDE + 64]);
  float L = 0.f, oo = 0.f;
#pragma unroll
  for (int i = 0; i < NSPLIT; ++i) {
    float w = expf(pb0[i * PSTRIDE + 64] - M);
    L = fmaf(pb0[i * PSTRIDE + 65], w, L);
    oo = fmaf(pb0[i * PSTRIDE + lane], w, oo);
  }
  attnb[(size_t)(bb * NTOK) * DIM + h * DHEAD + lane] = (__bf16)(oo / L);
}

// ---------------- launch ----------------
extern "C" void kernel_launch(void* const* d_in, const int* in_sizes, int n_in,
                              void* d_out, int out_size, void* d_ws, size_t ws_size,
                              hipStream_t stream) {
  const float* x = (const float*)d_in[0];
  const float* w_qkv = (const float*)d_in[1];
  const float* w_out = (const float*)d_in[2];
  const float* b_out = (const float*)d_in[3];
  float* out = (float*)d_out;

  char* ws = (char*)d_ws;
  __bf16* xb    = (__bf16*)(ws);                                   // MP*DIM      (6.49 MB)
  __bf16* wqkvT = (__bf16*)(ws + 6488064);                         // QKV3*DIM    (3.54 MB)
  __bf16* woutT = (__bf16*)(ws + 6488064 + 3538944);               // DIM*DIM     (1.18 MB)
  __bf16* qkvb  = (__bf16*)(ws + 6488064 + 3538944 + 1179648);     // MP*QKV3     (19.5 MB)
  __bf16* attnb = (__bf16*)(ws + 6488064 + 3538944 + 1179648 + 19464192); // MP*DIM (6.49 MB)
  int*    cnt   = (int*)  (ws + 6488064 + 3538944 + 1179648 + 19464192 + 6488064); // 24 ints
  float*  clsp  = (float*)(ws + 6488064 + 3538944 + 1179648 + 19464192 + 6488064 + 512);

  prep_kernel<<<PREP_BLOCKS, 256, 0, stream>>>(x, w_qkv, w_out, xb, wqkvT, woutT, cnt);

  gemm_qkv_kernel<<<(MP / 64) * (QKV3 / 128), 256, 0, stream>>>(xb, wqkvT, qkvb);

  attn_fused_kernel<<<WIN_BLOCKS + BATCH * HEADS * NSPLIT, 64, 0, stream>>>(qkvb, attnb, clsp, cnt);

  gemm_out_kernel<<<(MP / 64) * (DIM / 64), 256, 0, stream>>>(attnb, woutT, out, b_out);
}

// Round 11
// 148.381 us; speedup vs baseline: 1.2021x; 1.2021x over previous
//
#include <hip/hip_runtime.h>
#include <hip/hip_bf16.h>
#include <math.h>

typedef __attribute__((ext_vector_type(8))) __bf16 bf16x8;
typedef __attribute__((ext_vector_type(4))) float f32x4;

#define HEADS 12
#define DHEAD 64
#define NTOK 2049
#define BATCH 2
#define DIM 768
#define QKV3 2304
#define MROWS 4098   // BATCH*NTOK
#define MP 4224      // padded to 33*128 (and 66*64)
#define ATT_SCALE 0.125f
#define BKS 64
#define NSPLIT 33    // 33 chunks of 64 keys cover 2049
#define PSTRIDE 68   // floats per (b,h,split) partial record: o[64], m, l, pad

#define CVT_BLOCKS 1584
#define TQKV_BX 72
#define TQKV_BLOCKS (72 * 24)
#define TOUT_BX 24
#define TOUT_BLOCKS (24 * 24)
#define PREP_BLOCKS (CVT_BLOCKS + TQKV_BLOCKS + TOUT_BLOCKS)
#define WIN_BLOCKS (BATCH * 129 * 3)   // 774

// Bijective XCD chunk swizzle (m204): hardware block o -> work id, so that the
// 8-way round-robin XCD dispatch gives each XCD a CONTIGUOUS chunk of work ids.
__device__ __forceinline__ int xcd_swz(int o, int nwg) {
  const int q = nwg >> 3, r = nwg & 7;
  const int xcd = o & 7, i = o >> 3;
  return (xcd < r ? xcd * (q + 1) : r * (q + 1) + (xcd - r) * q) + i;
}

// ---------------- fused prep: cvt_x + transpose w_qkv + transpose w_out ----------------
__global__ __launch_bounds__(256) void prep_kernel(const float* __restrict__ x,
                                                   const float* __restrict__ w_qkv,
                                                   const float* __restrict__ w_out,
                                                   __bf16* __restrict__ xb,
                                                   __bf16* __restrict__ wqkvT,
                                                   __bf16* __restrict__ woutT) {
  __shared__ float tile[32][33];
  const int b = blockIdx.x, tid = threadIdx.x;
  if (b < CVT_BLOCKS) {
    long e = ((long)b * 256 + tid) * 8;   // 8 elems/thread, 768%8==0 keeps in-row
    int row = (int)(e / DIM);
    bf16x8 v;
    if (row < MROWS) {
      const float4 a = *(const float4*)(x + e);
      const float4 c = *(const float4*)(x + e + 4);
      v[0] = (__bf16)a.x; v[1] = (__bf16)a.y; v[2] = (__bf16)a.z; v[3] = (__bf16)a.w;
      v[4] = (__bf16)c.x; v[5] = (__bf16)c.y; v[6] = (__bf16)c.z; v[7] = (__bf16)c.w;
    } else {
#pragma unroll
      for (int j = 0; j < 8; ++j) v[j] = (__bf16)0.f;
    }
    *(bf16x8*)(xb + e) = v;
    return;
  }
  const float* in;
  __bf16* outp;
  int C, bx, by;
  if (b < CVT_BLOCKS + TQKV_BLOCKS) {
    int idx = b - CVT_BLOCKS;
    bx = idx % TQKV_BX; by = idx / TQKV_BX;
    in = w_qkv; outp = wqkvT; C = QKV3;
  } else {
    int idx = b - CVT_BLOCKS - TQKV_BLOCKS;
    bx = idx % TOUT_BX; by = idx / TOUT_BX;
    in = w_out; outp = woutT; C = DIM;
  }
  const int R = DIM;
  const int c0 = bx * 32, r0 = by * 32;
  const int tx = tid & 31, ty = tid >> 5;
#pragma unroll
  for (int i = 0; i < 4; ++i) {
    int r = ty + i * 8;
    tile[r][tx] = in[(size_t)(r0 + r) * C + c0 + tx];
  }
  __syncthreads();
#pragma unroll
  for (int i = 0; i < 4; ++i) {
    int r = ty + i * 8;
    outp[(size_t)(c0 + r) * R + r0 + tx] = (__bf16)tile[tx][r];
  }
}

// ---------------- qkv GEMM: C[M][2304] = xb[M][768] * wqkvT[2304][768]^T ----------------
// 64x128 tile, 1D grid 1188 with XCD m-band swizzle, 4 waves 2x2, BK=64,
// dbuf + prefetch-first, T2 swizzle via inverse-swizzled global source col.
__global__ __launch_bounds__(256) void gemm_qkv_kernel(const __bf16* __restrict__ A,
                                                       const __bf16* __restrict__ Bt,
                                                       __bf16* __restrict__ C) {
  __shared__ __bf16 sA[2][64 * BKS];
  __shared__ __bf16 sB[2][128 * BKS];
  const int wg = xcd_swz(blockIdx.x, (MP / 64) * (QKV3 / 128));  // by-major: chunk = A-band
  const int by = wg / (QKV3 / 128), bx = wg % (QKV3 / 128);
  const int tid = threadIdx.x;
  const int w = tid >> 6, lane = tid & 63;
  const int m0 = by * 64, n0 = bx * 128;
  const int wr = w >> 1, wc = w & 1;
  const int K = DIM;
  f32x4 acc[2][4] = {};

  const int srow = (w << 3) + (lane >> 3);                 // 0..31; +it*32 keeps row&7
  const int scolE = ((lane & 7) ^ (lane >> 3)) << 3;       // inverse-swizzled source col
  const __bf16* gA = A + (size_t)(m0 + srow) * K + scolE;
  const __bf16* gB = Bt + (size_t)(n0 + srow) * K + scolE;
  const int nk = K / BKS;  // 12

#define STAGE_Q(buf, kt)                                                                 \
  do {                                                                                   \
    _Pragma("unroll")                                                                    \
    for (int it = 0; it < 2; ++it) {                                                     \
      __builtin_amdgcn_global_load_lds(                                                  \
          (const __attribute__((address_space(1))) void*)(gA + (size_t)(it * 32) * K + (kt)), \
          (__attribute__((address_space(3))) void*)(&sA[buf][(it << 11) + (w << 9)]), 16, 0, 0); \
    }                                                                                    \
    _Pragma("unroll")                                                                    \
    for (int it = 0; it < 4; ++it) {                                                     \
      __builtin_amdgcn_global_load_lds(                                                  \
          (const __attribute__((address_space(1))) void*)(gB + (size_t)(it * 32) * K + (kt)), \
          (__attribute__((address_space(3))) void*)(&sB[buf][(it << 11) + (w << 9)]), 16, 0, 0); \
    }                                                                                    \
  } while (0)

  STAGE_Q(0, 0);
  __syncthreads();

  const int sw0 = ((lane >> 4) ^ (lane & 7)) << 3;   // kk=0 swizzled slot
  const int sw1 = sw0 ^ 32;                          // kk=32
  const int rofA = (wr * 32 + (lane & 15)) * BKS;
  const int rofB = (wc * 64 + (lane & 15)) * BKS;

  for (int t = 0; t < nk; ++t) {
    const int cur = t & 1;
    if (t + 1 < nk) STAGE_Q(cur ^ 1, (t + 1) * BKS);  // issue next-tile loads first
    const __bf16* bufA = sA[cur];
    const __bf16* bufB = sB[cur];
#pragma unroll
    for (int kk = 0; kk < BKS; kk += 32) {
      const int so = (kk == 0) ? sw0 : sw1;
      bf16x8 af[2], bfr[4];
#pragma unroll
      for (int m = 0; m < 2; ++m)
        af[m] = *(const bf16x8*)&bufA[rofA + m * 16 * BKS + so];
#pragma unroll
      for (int n = 0; n < 4; ++n)
        bfr[n] = *(const bf16x8*)&bufB[rofB + n * 16 * BKS + so];
#pragma unroll
      for (int m = 0; m < 2; ++m)
#pragma unroll
        for (int n = 0; n < 4; ++n)
          acc[m][n] = __builtin_amdgcn_mfma_f32_16x16x32_bf16(af[m], bfr[n], acc[m][n], 0, 0, 0);
    }
    __syncthreads();
  }
#undef STAGE_Q

#pragma unroll
  for (int m = 0; m < 2; ++m) {
#pragma unroll
    for (int n = 0; n < 4; ++n) {
      int col = n0 + wc * 64 + n * 16 + (lane & 15);
      int rbase = m0 + wr * 32 + m * 16 + ((lane >> 4) << 2);
#pragma unroll
      for (int r = 0; r < 4; ++r) {
        C[(size_t)(rbase + r) * QKV3 + col] = (__bf16)acc[m][n][r];
      }
    }
  }
}

// ---------------- out GEMM: out[M][768] = attnb[M][768]*woutT[768][768]^T + bias ----------------
// 64x64 tile, 1D grid 792 with XCD m-band swizzle, 4 waves 2x2, BK=64, dbuf, swizzle.
__global__ __launch_bounds__(256) void gemm_out_kernel(const __bf16* __restrict__ A,
                                                       const __bf16* __restrict__ Bt,
                                                       float* __restrict__ Cv,
                                                       const float* __restrict__ bias) {
  __shared__ __bf16 sA[2][64 * BKS];
  __shared__ __bf16 sB[2][64 * BKS];
  const int wg = xcd_swz(blockIdx.x, (MP / 64) * (DIM / 64));
  const int by = wg / (DIM / 64), bx = wg % (DIM / 64);
  const int tid = threadIdx.x;
  const int w = tid >> 6, lane = tid & 63;
  const int m0 = by * 64, n0 = bx * 64;
  const int wr = w >> 1, wc = w & 1;
  const int K = DIM, N = DIM;
  f32x4 acc[2][2] = {};

  const int srow = (w << 3) + (lane >> 3);
  const int scol = ((lane & 7) ^ (lane >> 3)) << 3;
  const __bf16* gA = A + (size_t)(m0 + srow) * K + scol;
  const __bf16* gB = Bt + (size_t)(n0 + srow) * K + scol;
  const int nk = K / BKS;

#define STAGE_O(buf, kt)                                                                 \
  do {                                                                                   \
    _Pragma("unroll")                                                                    \
    for (int it = 0; it < 2; ++it) {                                                     \
      __builtin_amdgcn_global_load_lds(                                                  \
          (const __attribute__((address_space(1))) void*)(gA + (size_t)(it * 32) * K + (kt)), \
          (__attribute__((address_space(3))) void*)(&sA[buf][(it << 11) + (w << 9)]), 16, 0, 0); \
      __builtin_amdgcn_global_load_lds(                                                  \
          (const __attribute__((address_space(1))) void*)(gB + (size_t)(it * 32) * K + (kt)), \
          (__attribute__((address_space(3))) void*)(&sB[buf][(it << 11) + (w << 9)]), 16, 0, 0); \
    }                                                                                    \
  } while (0)

  STAGE_O(0, 0);
  __syncthreads();

  const int sw0 = ((lane >> 4) ^ (lane & 7)) << 3;
  const int sw1 = sw0 ^ 32;
  const int rofA = (wr * 32 + (lane & 15)) * BKS;
  const int rofB = (wc * 32 + (lane & 15)) * BKS;

  for (int t = 0; t < nk; ++t) {
    const int cur = t & 1;
    if (t + 1 < nk) STAGE_O(cur ^ 1, (t + 1) * BKS);
    const __bf16* bufA = sA[cur];
    const __bf16* bufB = sB[cur];
#pragma unroll
    for (int kk = 0; kk < BKS; kk += 32) {
      const int so = (kk == 0) ? sw0 : sw1;
      bf16x8 af[2], bfr[2];
#pragma unroll
      for (int m = 0; m < 2; ++m)
        af[m] = *(const bf16x8*)&bufA[rofA + m * 16 * BKS + so];
#pragma unroll
      for (int n = 0; n < 2; ++n)
        bfr[n] = *(const bf16x8*)&bufB[rofB + n * 16 * BKS + so];
#pragma unroll
      for (int m = 0; m < 2; ++m)
#pragma unroll
        for (int n = 0; n < 2; ++n)
          acc[m][n] = __builtin_amdgcn_mfma_f32_16x16x32_bf16(af[m], bfr[n], acc[m][n], 0, 0, 0);
    }
    __syncthreads();
  }
#undef STAGE_O

#pragma unroll
  for (int m = 0; m < 2; ++m) {
#pragma unroll
    for (int n = 0; n < 2; ++n) {
      int col = n0 + wc * 32 + n * 16 + (lane & 15);
      int rbase = m0 + wr * 32 + m * 16 + ((lane >> 4) << 2);
#pragma unroll
      for (int r = 0; r < 4; ++r) {
        int row = rbase + r;
        if (row < MROWS) Cv[(size_t)row * N + col] = acc[m][n][r] + bias[col];
      }
    }
  }
}

// ---------------- fused attention: windows (t>=1, two-pass) + CLS split-K partials ----------------
__global__ __launch_bounds__(64) void attn_fused_kernel(const __bf16* __restrict__ qkv,
                                                        __bf16* __restrict__ attnb,
                                                        float* __restrict__ part) {
  __shared__ float sp_lds[64];
  const int lane = threadIdx.x;

  if (blockIdx.x < WIN_BLOCKS) {
    int bidx = blockIdx.x;
    int hg = bidx % 3; bidx /= 3;
    int blk = bidx % 129;
    int bb = bidx / 129;
    int h = hg * 4 + (lane >> 4);
    int qi = lane & 15;
    int t0 = (blk == 0) ? 1 : 2 + 16 * (blk - 1);
    int nt = (blk == 0) ? 1 : ((NTOK - t0) < 16 ? (NTOK - t0) : 16);
    bool active = qi < nt;
    int qt = t0 + (active ? qi : nt - 1);
    const size_t base = (size_t)bb * NTOK * QKV3;

    float q[64];
    {
      const __bf16* qp = qkv + base + (size_t)qt * QKV3 + h * DHEAD;
#pragma unroll
      for (int d0 = 0; d0 < 64; d0 += 8) {
        bf16x8 v = *(const bf16x8*)(qp + d0);
#pragma unroll
        for (int j = 0; j < 8; ++j) q[d0 + j] = (float)v[j];
      }
    }

    float s[17];
    float mx = -3.4e38f;
#pragma unroll
    for (int j = 0; j < 17; ++j) {
      int jc = (j - 1) < (nt - 1) ? (j - 1) : (nt - 1);
      int kt = (j == 0) ? 0 : t0 + jc;
      const __bf16* kp = qkv + base + (size_t)kt * QKV3 + DIM + h * DHEAD;
      float dot = 0.f;
#pragma unroll
      for (int d0 = 0; d0 < 64; d0 += 8) {
        bf16x8 v = *(const bf16x8*)(kp + d0);
#pragma unroll
        for (int jj = 0; jj < 8; ++jj) dot = fmaf(q[d0 + jj], (float)v[jj], dot);
      }
      s[j] = (j <= nt) ? dot * ATT_SCALE : -3.4e38f;
      mx = fmaxf(mx, s[j]);
    }
    float sum = 0.f;
#pragma unroll
    for (int j = 0; j < 17; ++j) {
      s[j] = expf(s[j] - mx);
      sum += s[j];
    }
    float inv = 1.f / sum;

    float o[64];
#pragma unroll
    for (int d = 0; d < 64; ++d) o[d] = 0.f;
#pragma unroll
    for (int j = 0; j < 17; ++j) {
      int jc = (j - 1) < (nt - 1) ? (j - 1) : (nt - 1);
      int vt = (j == 0) ? 0 : t0 + jc;
      const __bf16* vp = qkv + base + (size_t)vt * QKV3 + 2 * DIM + h * DHEAD;
      float p = s[j];
#pragma unroll
      for (int d0 = 0; d0 < 64; d0 += 8) {
        bf16x8 v = *(const bf16x8*)(vp + d0);
#pragma unroll
        for (int jj = 0; jj < 8; ++jj) o[d0 + jj] = fmaf(p, (float)v[jj], o[d0 + jj]);
      }
    }

    if (active) {
      __bf16* op = attnb + (size_t)(bb * NTOK + qt) * DIM + h * DHEAD;
#pragma unroll
      for (int d0 = 0; d0 < 64; d0 += 8) {
        bf16x8 v;
#pragma unroll
        for (int j = 0; j < 8; ++j) v[j] = (__bf16)(o[d0 + j] * inv);
        *(bf16x8*)(op + d0) = v;
      }
    }
    return;
  }

  int bid = blockIdx.x - WIN_BLOCKS;
  const int sp = bid % NSPLIT;
  const int bh = bid / NSPLIT;
  const int h = bh % HEADS;
  const int bb = bh / HEADS;
  const size_t base = (size_t)bb * NTOK * QKV3;

  float q[64];
  {
    const __bf16* qp = qkv + base + h * DHEAD;
#pragma unroll
    for (int d0 = 0; d0 < 64; d0 += 8) {
      bf16x8 v = *(const bf16x8*)(qp + d0);
#pragma unroll
      for (int j = 0; j < 8; ++j) q[d0 + j] = (float)v[j];
    }
  }

  const int t = sp * 64 + lane;
  const bool valid = t < NTOK;
  const int tc = valid ? t : NTOK - 1;
  float dot = 0.f;
  {
    const __bf16* kp = qkv + base + (size_t)tc * QKV3 + DIM + h * DHEAD;
#pragma unroll
    for (int d0 = 0; d0 < 64; d0 += 8) {
      bf16x8 v = *(const bf16x8*)(kp + d0);
#pragma unroll
      for (int j = 0; j < 8; ++j) dot = fmaf(q[d0 + j], (float)v[j], dot);
    }
  }
  float s = valid ? dot * ATT_SCALE : -3.4e38f;

  float m = s;
#pragma unroll
  for (int off = 32; off > 0; off >>= 1) m = fmaxf(m, __shfl_xor(m, off, 64));
  float p = valid ? expf(s - m) : 0.f;
  float l = p;
#pragma unroll
  for (int off = 32; off > 0; off >>= 1) l += __shfl_xor(l, off, 64);

  sp_lds[lane] = p;
  __syncthreads();

  const int nt = (NTOK - sp * 64) < 64 ? (NTOK - sp * 64) : 64;
  float o = 0.f;
  const __bf16* vcol = qkv + base + (size_t)(sp * 64) * QKV3 + 2 * DIM + h * DHEAD + lane;
  for (int tt = 0; tt < nt; ++tt) {
    o = fmaf(sp_lds[tt], (float)vcol[(size_t)tt * QKV3], o);
  }

  float* pb = part + ((size_t)bh * NSPLIT + sp) * PSTRIDE;
  pb[lane] = o;
  if (lane == 0) { pb[64] = m; pb[65] = l; }
}

__global__ __launch_bounds__(64) void attn_cls_reduce(const float* __restrict__ part,
                                                      __bf16* __restrict__ attnb) {
  const int bh = blockIdx.x;
  const int h = bh % HEADS;
  const int bb = bh / HEADS;
  const int lane = threadIdx.x;
  const float* pb0 = part + (size_t)bh * NSPLIT * PSTRIDE;
  float M = -3.4e38f;
#pragma unroll
  for (int i = 0; i < NSPLIT; ++i) M = fmaxf(M, pb0[i * PSTRIDE + 64]);
  float L = 0.f, o = 0.f;
#pragma unroll
  for (int i = 0; i < NSPLIT; ++i) {
    float w = expf(pb0[i * PSTRIDE + 64] - M);
    L = fmaf(pb0[i * PSTRIDE + 65], w, L);
    o = fmaf(pb0[i * PSTRIDE + lane], w, o);
  }
  attnb[(size_t)(bb * NTOK) * DIM + h * DHEAD + lane] = (__bf16)(o / L);
}

// ---------------- launch ----------------
extern "C" void kernel_launch(void* const* d_in, const int* in_sizes, int n_in,
                              void* d_out, int out_size, void* d_ws, size_t ws_size,
                              hipStream_t stream) {
  const float* x = (const float*)d_in[0];
  const float* w_qkv = (const float*)d_in[1];
  const float* w_out = (const float*)d_in[2];
  const float* b_out = (const float*)d_in[3];
  float* out = (float*)d_out;

  char* ws = (char*)d_ws;
  __bf16* xb    = (__bf16*)(ws);                                   // MP*DIM      (6.49 MB)
  __bf16* wqkvT = (__bf16*)(ws + 6488064);                         // QKV3*DIM    (3.54 MB)
  __bf16* woutT = (__bf16*)(ws + 6488064 + 3538944);               // DIM*DIM     (1.18 MB)
  __bf16* qkvb  = (__bf16*)(ws + 6488064 + 3538944 + 1179648);     // MP*QKV3     (19.5 MB)
  __bf16* attnb = (__bf16*)(ws + 6488064 + 3538944 + 1179648 + 19464192); // MP*DIM (6.49 MB)
  float*  clsp  = (float*)(ws + 6488064 + 3538944 + 1179648 + 19464192 + 6488064); // 24*33*68*4 B

  prep_kernel<<<PREP_BLOCKS, 256, 0, stream>>>(x, w_qkv, w_out, xb, wqkvT, woutT);

  gemm_qkv_kernel<<<(MP / 64) * (QKV3 / 128), 256, 0, stream>>>(xb, wqkvT, qkvb);

  attn_fused_kernel<<<WIN_BLOCKS + BATCH * HEADS * NSPLIT, 64, 0, stream>>>(qkvb, attnb, clsp);
  attn_cls_reduce<<<BATCH * HEADS, 64, 0, stream>>>(clsp, attnb);

  gemm_out_kernel<<<(MP / 64) * (DIM / 64), 256, 0, stream>>>(attnb, woutT, out, b_out);
}

// Round 12
// 140.877 us; speedup vs baseline: 1.2661x; 1.0533x over previous
//
#include <hip/hip_runtime.h>
#include <hip/hip_bf16.h>
#include <math.h>

typedef __attribute__((ext_vector_type(8))) __bf16 bf16x8;
typedef __attribute__((ext_vector_type(4))) float f32x4;

#define HEADS 12
#define DHEAD 64
#define NTOK 2049
#define BATCH 2
#define DIM 768
#define QKV3 2304
#define MROWS 4098   // BATCH*NTOK
#define MP 4224      // padded to 33*128 (and 66*64)
#define ATT_SCALE 0.125f
#define BKS 64
#define NSPLIT 33    // 33 chunks of 64 keys cover 2049
#define PSTRIDE 68   // floats per (b,h,split) partial record: o[64], m, l, pad

#define CVT_BLOCKS 1584
#define TQKV_BX 72
#define TQKV_BLOCKS (72 * 24)
#define TOUT_BX 24
#define TOUT_BLOCKS (24 * 24)
#define PREP_BLOCKS (CVT_BLOCKS + TQKV_BLOCKS + TOUT_BLOCKS)
#define WIN_BLOCKS (BATCH * 129 * HEADS)   // 3096: one wave per (b, blk, head)

// Bijective XCD chunk swizzle (m204): hardware block o -> work id, so that the
// 8-way round-robin XCD dispatch gives each XCD a CONTIGUOUS chunk of work ids.
__device__ __forceinline__ int xcd_swz(int o, int nwg) {
  const int q = nwg >> 3, r = nwg & 7;
  const int xcd = o & 7, i = o >> 3;
  return (xcd < r ? xcd * (q + 1) : r * (q + 1) + (xcd - r) * q) + i;
}

// ---------------- fused prep: cvt_x + transpose w_qkv + transpose w_out ----------------
__global__ __launch_bounds__(256) void prep_kernel(const float* __restrict__ x,
                                                   const float* __restrict__ w_qkv,
                                                   const float* __restrict__ w_out,
                                                   __bf16* __restrict__ xb,
                                                   __bf16* __restrict__ wqkvT,
                                                   __bf16* __restrict__ woutT) {
  __shared__ float tile[32][33];
  const int b = blockIdx.x, tid = threadIdx.x;
  if (b < CVT_BLOCKS) {
    long e = ((long)b * 256 + tid) * 8;   // 8 elems/thread, 768%8==0 keeps in-row
    int row = (int)(e / DIM);
    bf16x8 v;
    if (row < MROWS) {
      const float4 a = *(const float4*)(x + e);
      const float4 c = *(const float4*)(x + e + 4);
      v[0] = (__bf16)a.x; v[1] = (__bf16)a.y; v[2] = (__bf16)a.z; v[3] = (__bf16)a.w;
      v[4] = (__bf16)c.x; v[5] = (__bf16)c.y; v[6] = (__bf16)c.z; v[7] = (__bf16)c.w;
    } else {
#pragma unroll
      for (int j = 0; j < 8; ++j) v[j] = (__bf16)0.f;
    }
    *(bf16x8*)(xb + e) = v;
    return;
  }
  const float* in;
  __bf16* outp;
  int C, bx, by;
  if (b < CVT_BLOCKS + TQKV_BLOCKS) {
    int idx = b - CVT_BLOCKS;
    bx = idx % TQKV_BX; by = idx / TQKV_BX;
    in = w_qkv; outp = wqkvT; C = QKV3;
  } else {
    int idx = b - CVT_BLOCKS - TQKV_BLOCKS;
    bx = idx % TOUT_BX; by = idx / TOUT_BX;
    in = w_out; outp = woutT; C = DIM;
  }
  const int R = DIM;
  const int c0 = bx * 32, r0 = by * 32;
  const int tx = tid & 31, ty = tid >> 5;
#pragma unroll
  for (int i = 0; i < 4; ++i) {
    int r = ty + i * 8;
    tile[r][tx] = in[(size_t)(r0 + r) * C + c0 + tx];
  }
  __syncthreads();
#pragma unroll
  for (int i = 0; i < 4; ++i) {
    int r = ty + i * 8;
    outp[(size_t)(c0 + r) * R + r0 + tx] = (__bf16)tile[tx][r];
  }
}

// ---------------- qkv GEMM: C[M][2304] = xb[M][768] * wqkvT[2304][768]^T ----------------
// 64x128 tile, 1D grid 1188 with XCD m-band swizzle, 4 waves 2x2, BK=64,
// dbuf + prefetch-first, T2 swizzle via inverse-swizzled global source col.
__global__ __launch_bounds__(256) void gemm_qkv_kernel(const __bf16* __restrict__ A,
                                                       const __bf16* __restrict__ Bt,
                                                       __bf16* __restrict__ C) {
  __shared__ __bf16 sA[2][64 * BKS];
  __shared__ __bf16 sB[2][128 * BKS];
  const int wg = xcd_swz(blockIdx.x, (MP / 64) * (QKV3 / 128));  // by-major: chunk = A-band
  const int by = wg / (QKV3 / 128), bx = wg % (QKV3 / 128);
  const int tid = threadIdx.x;
  const int w = tid >> 6, lane = tid & 63;
  const int m0 = by * 64, n0 = bx * 128;
  const int wr = w >> 1, wc = w & 1;
  const int K = DIM;
  f32x4 acc[2][4] = {};

  const int srow = (w << 3) + (lane >> 3);                 // 0..31; +it*32 keeps row&7
  const int scolE = ((lane & 7) ^ (lane >> 3)) << 3;       // inverse-swizzled source col
  const __bf16* gA = A + (size_t)(m0 + srow) * K + scolE;
  const __bf16* gB = Bt + (size_t)(n0 + srow) * K + scolE;
  const int nk = K / BKS;  // 12

#define STAGE_Q(buf, kt)                                                                 \
  do {                                                                                   \
    _Pragma("unroll")                                                                    \
    for (int it = 0; it < 2; ++it) {                                                     \
      __builtin_amdgcn_global_load_lds(                                                  \
          (const __attribute__((address_space(1))) void*)(gA + (size_t)(it * 32) * K + (kt)), \
          (__attribute__((address_space(3))) void*)(&sA[buf][(it << 11) + (w << 9)]), 16, 0, 0); \
    }                                                                                    \
    _Pragma("unroll")                                                                    \
    for (int it = 0; it < 4; ++it) {                                                     \
      __builtin_amdgcn_global_load_lds(                                                  \
          (const __attribute__((address_space(1))) void*)(gB + (size_t)(it * 32) * K + (kt)), \
          (__attribute__((address_space(3))) void*)(&sB[buf][(it << 11) + (w << 9)]), 16, 0, 0); \
    }                                                                                    \
  } while (0)

  STAGE_Q(0, 0);
  __syncthreads();

  const int sw0 = ((lane >> 4) ^ (lane & 7)) << 3;   // kk=0 swizzled slot
  const int sw1 = sw0 ^ 32;                          // kk=32
  const int rofA = (wr * 32 + (lane & 15)) * BKS;
  const int rofB = (wc * 64 + (lane & 15)) * BKS;

  for (int t = 0; t < nk; ++t) {
    const int cur = t & 1;
    if (t + 1 < nk) STAGE_Q(cur ^ 1, (t + 1) * BKS);  // issue next-tile loads first
    const __bf16* bufA = sA[cur];
    const __bf16* bufB = sB[cur];
#pragma unroll
    for (int kk = 0; kk < BKS; kk += 32) {
      const int so = (kk == 0) ? sw0 : sw1;
      bf16x8 af[2], bfr[4];
#pragma unroll
      for (int m = 0; m < 2; ++m)
        af[m] = *(const bf16x8*)&bufA[rofA + m * 16 * BKS + so];
#pragma unroll
      for (int n = 0; n < 4; ++n)
        bfr[n] = *(const bf16x8*)&bufB[rofB + n * 16 * BKS + so];
#pragma unroll
      for (int m = 0; m < 2; ++m)
#pragma unroll
        for (int n = 0; n < 4; ++n)
          acc[m][n] = __builtin_amdgcn_mfma_f32_16x16x32_bf16(af[m], bfr[n], acc[m][n], 0, 0, 0);
    }
    __syncthreads();
  }
#undef STAGE_Q

#pragma unroll
  for (int m = 0; m < 2; ++m) {
#pragma unroll
    for (int n = 0; n < 4; ++n) {
      int col = n0 + wc * 64 + n * 16 + (lane & 15);
      int rbase = m0 + wr * 32 + m * 16 + ((lane >> 4) << 2);
#pragma unroll
      for (int r = 0; r < 4; ++r) {
        C[(size_t)(rbase + r) * QKV3 + col] = (__bf16)acc[m][n][r];
      }
    }
  }
}

// ---------------- out GEMM: out[M][768] = attnb[M][768]*woutT[768][768]^T + bias ----------------
// 64x64 tile, 1D grid 792 with XCD m-band swizzle, 4 waves 2x2, BK=64, dbuf, swizzle.
__global__ __launch_bounds__(256) void gemm_out_kernel(const __bf16* __restrict__ A,
                                                       const __bf16* __restrict__ Bt,
                                                       float* __restrict__ Cv,
                                                       const float* __restrict__ bias) {
  __shared__ __bf16 sA[2][64 * BKS];
  __shared__ __bf16 sB[2][64 * BKS];
  const int wg = xcd_swz(blockIdx.x, (MP / 64) * (DIM / 64));
  const int by = wg / (DIM / 64), bx = wg % (DIM / 64);
  const int tid = threadIdx.x;
  const int w = tid >> 6, lane = tid & 63;
  const int m0 = by * 64, n0 = bx * 64;
  const int wr = w >> 1, wc = w & 1;
  const int K = DIM, N = DIM;
  f32x4 acc[2][2] = {};

  const int srow = (w << 3) + (lane >> 3);
  const int scol = ((lane & 7) ^ (lane >> 3)) << 3;
  const __bf16* gA = A + (size_t)(m0 + srow) * K + scol;
  const __bf16* gB = Bt + (size_t)(n0 + srow) * K + scol;
  const int nk = K / BKS;

#define STAGE_O(buf, kt)                                                                 \
  do {                                                                                   \
    _Pragma("unroll")                                                                    \
    for (int it = 0; it < 2; ++it) {                                                     \
      __builtin_amdgcn_global_load_lds(                                                  \
          (const __attribute__((address_space(1))) void*)(gA + (size_t)(it * 32) * K + (kt)), \
          (__attribute__((address_space(3))) void*)(&sA[buf][(it << 11) + (w << 9)]), 16, 0, 0); \
      __builtin_amdgcn_global_load_lds(                                                  \
          (const __attribute__((address_space(1))) void*)(gB + (size_t)(it * 32) * K + (kt)), \
          (__attribute__((address_space(3))) void*)(&sB[buf][(it << 11) + (w << 9)]), 16, 0, 0); \
    }                                                                                    \
  } while (0)

  STAGE_O(0, 0);
  __syncthreads();

  const int sw0 = ((lane >> 4) ^ (lane & 7)) << 3;
  const int sw1 = sw0 ^ 32;
  const int rofA = (wr * 32 + (lane & 15)) * BKS;
  const int rofB = (wc * 32 + (lane & 15)) * BKS;

  for (int t = 0; t < nk; ++t) {
    const int cur = t & 1;
    if (t + 1 < nk) STAGE_O(cur ^ 1, (t + 1) * BKS);
    const __bf16* bufA = sA[cur];
    const __bf16* bufB = sB[cur];
#pragma unroll
    for (int kk = 0; kk < BKS; kk += 32) {
      const int so = (kk == 0) ? sw0 : sw1;
      bf16x8 af[2], bfr[2];
#pragma unroll
      for (int m = 0; m < 2; ++m)
        af[m] = *(const bf16x8*)&bufA[rofA + m * 16 * BKS + so];
#pragma unroll
      for (int n = 0; n < 2; ++n)
        bfr[n] = *(const bf16x8*)&bufB[rofB + n * 16 * BKS + so];
#pragma unroll
      for (int m = 0; m < 2; ++m)
#pragma unroll
        for (int n = 0; n < 2; ++n)
          acc[m][n] = __builtin_amdgcn_mfma_f32_16x16x32_bf16(af[m], bfr[n], acc[m][n], 0, 0, 0);
    }
    __syncthreads();
  }
#undef STAGE_O

#pragma unroll
  for (int m = 0; m < 2; ++m) {
#pragma unroll
    for (int n = 0; n < 2; ++n) {
      int col = n0 + wc * 32 + n * 16 + (lane & 15);
      int rbase = m0 + wr * 32 + m * 16 + ((lane >> 4) << 2);
#pragma unroll
      for (int r = 0; r < 4; ++r) {
        int row = rbase + r;
        if (row < MROWS) Cv[(size_t)row * N + col] = acc[m][n][r] + bias[col];
      }
    }
  }
}

// ---------------- fused attention ----------------
// Windowed (t>=1): one wave per (b, blk, head); lane = (query qi = lane>>2,
// dim-quarter dq = lane&3). Each lane owns 16 dims; dots finished by 2 shfl_xor
// within the 4-lane group. Two-pass softmax, no LDS, no fences (R7/R9/R10 lessons).
// CLS (t=0): split-K partials, unchanged.
__global__ __launch_bounds__(64) void attn_fused_kernel(const __bf16* __restrict__ qkv,
                                                        __bf16* __restrict__ attnb,
                                                        float* __restrict__ part) {
  __shared__ float sp_lds[64];
  const int lane = threadIdx.x;

  if (blockIdx.x < WIN_BLOCKS) {
    int bidx = blockIdx.x;
    const int h = bidx % HEADS; bidx /= HEADS;
    const int blk = bidx % 129;
    const int bb = bidx / 129;
    const int qi = lane >> 2;          // 0..15
    const int dq = lane & 3;           // 0..3 -> dims [dq*16, dq*16+16)
    const int t0 = (blk == 0) ? 1 : 2 + 16 * (blk - 1);
    const int nt = (blk == 0) ? 1 : ((NTOK - t0) < 16 ? (NTOK - t0) : 16);
    const bool active = qi < nt;
    const int qt = t0 + (active ? qi : nt - 1);
    const size_t base = (size_t)bb * NTOK * QKV3;
    const int dbase = h * DHEAD + dq * 16;

    float q[16];
    {
      const __bf16* qp = qkv + base + (size_t)qt * QKV3 + dbase;
      bf16x8 v0 = *(const bf16x8*)qp;
      bf16x8 v1 = *(const bf16x8*)(qp + 8);
#pragma unroll
      for (int j = 0; j < 8; ++j) { q[j] = (float)v0[j]; q[8 + j] = (float)v1[j]; }
    }

    float s[17];
    float mx = -3.4e38f;
#pragma unroll
    for (int j = 0; j < 17; ++j) {
      int jc = (j - 1) < (nt - 1) ? (j - 1) : (nt - 1);
      int kt = (j == 0) ? 0 : t0 + jc;
      const __bf16* kp = qkv + base + (size_t)kt * QKV3 + DIM + dbase;
      bf16x8 v0 = *(const bf16x8*)kp;
      bf16x8 v1 = *(const bf16x8*)(kp + 8);
      float dot = 0.f;
#pragma unroll
      for (int jj = 0; jj < 8; ++jj) {
        dot = fmaf(q[jj], (float)v0[jj], dot);
        dot = fmaf(q[8 + jj], (float)v1[jj], dot);
      }
      dot += __shfl_xor(dot, 1, 64);   // combine the 4 dim-quarters
      dot += __shfl_xor(dot, 2, 64);
      s[j] = (j <= nt) ? dot * ATT_SCALE : -3.4e38f;
      mx = fmaxf(mx, s[j]);
    }
    float sum = 0.f;
#pragma unroll
    for (int j = 0; j < 17; ++j) {
      s[j] = expf(s[j] - mx);          // identical across the 4-lane group
      sum += s[j];
    }
    float inv = 1.f / sum;

    float o[16];
#pragma unroll
    for (int d = 0; d < 16; ++d) o[d] = 0.f;
#pragma unroll
    for (int j = 0; j < 17; ++j) {
      int jc = (j - 1) < (nt - 1) ? (j - 1) : (nt - 1);
      int vt = (j == 0) ? 0 : t0 + jc;
      const __bf16* vp = qkv + base + (size_t)vt * QKV3 + 2 * DIM + dbase;
      bf16x8 v0 = *(const bf16x8*)vp;
      bf16x8 v1 = *(const bf16x8*)(vp + 8);
      float p = s[j];
#pragma unroll
      for (int jj = 0; jj < 8; ++jj) {
        o[jj] = fmaf(p, (float)v0[jj], o[jj]);
        o[8 + jj] = fmaf(p, (float)v1[jj], o[8 + jj]);
      }
    }

    if (active) {
      __bf16* op = attnb + (size_t)(bb * NTOK + qt) * DIM + dbase;
      bf16x8 w0, w1;
#pragma unroll
      for (int j = 0; j < 8; ++j) {
        w0[j] = (__bf16)(o[j] * inv);
        w1[j] = (__bf16)(o[8 + j] * inv);
      }
      *(bf16x8*)op = w0;
      *(bf16x8*)(op + 8) = w1;
    }
    return;
  }

  // ---- CLS split-K partials: 1 wave per (b, h, 64-key chunk) ----
  int bid = blockIdx.x - WIN_BLOCKS;
  const int sp = bid % NSPLIT;
  const int bh = bid / NSPLIT;
  const int h = bh % HEADS;
  const int bb = bh / HEADS;
  const size_t base = (size_t)bb * NTOK * QKV3;

  float q[64];
  {
    const __bf16* qp = qkv + base + h * DHEAD;
#pragma unroll
    for (int d0 = 0; d0 < 64; d0 += 8) {
      bf16x8 v = *(const bf16x8*)(qp + d0);
#pragma unroll
      for (int j = 0; j < 8; ++j) q[d0 + j] = (float)v[j];
    }
  }

  const int t = sp * 64 + lane;
  const bool valid = t < NTOK;
  const int tc = valid ? t : NTOK - 1;
  float dot = 0.f;
  {
    const __bf16* kp = qkv + base + (size_t)tc * QKV3 + DIM + h * DHEAD;
#pragma unroll
    for (int d0 = 0; d0 < 64; d0 += 8) {
      bf16x8 v = *(const bf16x8*)(kp + d0);
#pragma unroll
      for (int j = 0; j < 8; ++j) dot = fmaf(q[d0 + j], (float)v[j], dot);
    }
  }
  float s = valid ? dot * ATT_SCALE : -3.4e38f;

  float m = s;
#pragma unroll
  for (int off = 32; off > 0; off >>= 1) m = fmaxf(m, __shfl_xor(m, off, 64));
  float p = valid ? expf(s - m) : 0.f;
  float l = p;
#pragma unroll
  for (int off = 32; off > 0; off >>= 1) l += __shfl_xor(l, off, 64);

  sp_lds[lane] = p;
  __syncthreads();

  const int nt = (NTOK - sp * 64) < 64 ? (NTOK - sp * 64) : 64;
  float o = 0.f;
  const __bf16* vcol = qkv + base + (size_t)(sp * 64) * QKV3 + 2 * DIM + h * DHEAD + lane;
  for (int tt = 0; tt < nt; ++tt) {
    o = fmaf(sp_lds[tt], (float)vcol[(size_t)tt * QKV3], o);
  }

  float* pb = part + ((size_t)bh * NSPLIT + sp) * PSTRIDE;
  pb[lane] = o;
  if (lane == 0) { pb[64] = m; pb[65] = l; }
}

__global__ __launch_bounds__(64) void attn_cls_reduce(const float* __restrict__ part,
                                                      __bf16* __restrict__ attnb) {
  const int bh = blockIdx.x;
  const int h = bh % HEADS;
  const int bb = bh / HEADS;
  const int lane = threadIdx.x;
  const float* pb0 = part + (size_t)bh * NSPLIT * PSTRIDE;
  float M = -3.4e38f;
#pragma unroll
  for (int i = 0; i < NSPLIT; ++i) M = fmaxf(M, pb0[i * PSTRIDE + 64]);
  float L = 0.f, o = 0.f;
#pragma unroll
  for (int i = 0; i < NSPLIT; ++i) {
    float w = expf(pb0[i * PSTRIDE + 64] - M);
    L = fmaf(pb0[i * PSTRIDE + 65], w, L);
    o = fmaf(pb0[i * PSTRIDE + lane], w, o);
  }
  attnb[(size_t)(bb * NTOK) * DIM + h * DHEAD + lane] = (__bf16)(o / L);
}

// ---------------- launch ----------------
extern "C" void kernel_launch(void* const* d_in, const int* in_sizes, int n_in,
                              void* d_out, int out_size, void* d_ws, size_t ws_size,
                              hipStream_t stream) {
  const float* x = (const float*)d_in[0];
  const float* w_qkv = (const float*)d_in[1];
  const float* w_out = (const float*)d_in[2];
  const float* b_out = (const float*)d_in[3];
  float* out = (float*)d_out;

  char* ws = (char*)d_ws;
  __bf16* xb    = (__bf16*)(ws);                                   // MP*DIM      (6.49 MB)
  __bf16* wqkvT = (__bf16*)(ws + 6488064);                         // QKV3*DIM    (3.54 MB)
  __bf16* woutT = (__bf16*)(ws + 6488064 + 3538944);               // DIM*DIM     (1.18 MB)
  __bf16* qkvb  = (__bf16*)(ws + 6488064 + 3538944 + 1179648);     // MP*QKV3     (19.5 MB)
  __bf16* attnb = (__bf16*)(ws + 6488064 + 3538944 + 1179648 + 19464192); // MP*DIM (6.49 MB)
  float*  clsp  = (float*)(ws + 6488064 + 3538944 + 1179648 + 19464192 + 6488064); // 24*33*68*4 B

  prep_kernel<<<PREP_BLOCKS, 256, 0, stream>>>(x, w_qkv, w_out, xb, wqkvT, woutT);

  gemm_qkv_kernel<<<(MP / 64) * (QKV3 / 128), 256, 0, stream>>>(xb, wqkvT, qkvb);

  attn_fused_kernel<<<WIN_BLOCKS + BATCH * HEADS * NSPLIT, 64, 0, stream>>>(qkvb, attnb, clsp);
  attn_cls_reduce<<<BATCH * HEADS, 64, 0, stream>>>(clsp, attnb);

  gemm_out_kernel<<<(MP / 64) * (DIM / 64), 256, 0, stream>>>(attnb, woutT, out, b_out);
}

// Round 14
// 140.624 us; speedup vs baseline: 1.2684x; 1.0018x over previous
//
#include <hip/hip_runtime.h>
#include <hip/hip_bf16.h>
#include <math.h>

typedef __attribute__((ext_vector_type(8))) __bf16 bf16x8;
typedef __attribute__((ext_vector_type(4))) __bf16 bf16x4;
typedef __attribute__((ext_vector_type(4))) float f32x4;

#define HEADS 12
#define DHEAD 64
#define NTOK 2049
#define BATCH 2
#define DIM 768
#define QKV3 2304
#define MROWS 4098   // BATCH*NTOK
#define MP 4224      // padded to 33*128 (and 66*64)
#define ATT_SCALE 0.125f
#define BKS 64
#define NSPLIT 33    // 33 chunks of 64 keys cover 2049
#define PSTRIDE 68   // floats per (b,h,split) partial record: o[64], m, l, pad

#define CVT_BLOCKS 1584
#define TQKV_BX 36   // 2304/64
#define TQKV_BLOCKS (36 * 12)
#define TOUT_BX 12   // 768/64
#define TOUT_BLOCKS (12 * 12)
#define PREP_BLOCKS (CVT_BLOCKS + TQKV_BLOCKS + TOUT_BLOCKS)
#define WIN_BLOCKS (BATCH * 129 * HEADS * 2)   // 6192: wave per (b, blk, head, half-window)

// Bijective XCD chunk swizzle (m204): hardware block o -> work id, so that the
// 8-way round-robin XCD dispatch gives each XCD a CONTIGUOUS chunk of work ids.
__device__ __forceinline__ int xcd_swz(int o, int nwg) {
  const int q = nwg >> 3, r = nwg & 7;
  const int xcd = o & 7, i = o >> 3;
  return (xcd < r ? xcd * (q + 1) : r * (q + 1) + (xcd - r) * q) + i;
}

// ---------------- fused prep: cvt_x + transpose w_qkv + transpose w_out ----------------
// Transposes use 64x64 tiles with bf16x4 (8 B) stores: 128 B per 16-lane group.
__global__ __launch_bounds__(256) void prep_kernel(const float* __restrict__ x,
                                                   const float* __restrict__ w_qkv,
                                                   const float* __restrict__ w_out,
                                                   __bf16* __restrict__ xb,
                                                   __bf16* __restrict__ wqkvT,
                                                   __bf16* __restrict__ woutT) {
  __shared__ float tile[64][65];   // 16.6 KB
  const int b = blockIdx.x, tid = threadIdx.x;
  if (b < CVT_BLOCKS) {
    long e = ((long)b * 256 + tid) * 8;   // 8 elems/thread, 768%8==0 keeps in-row
    int row = (int)(e / DIM);
    bf16x8 v;
    if (row < MROWS) {
      const float4 a = *(const float4*)(x + e);
      const float4 c = *(const float4*)(x + e + 4);
      v[0] = (__bf16)a.x; v[1] = (__bf16)a.y; v[2] = (__bf16)a.z; v[3] = (__bf16)a.w;
      v[4] = (__bf16)c.x; v[5] = (__bf16)c.y; v[6] = (__bf16)c.z; v[7] = (__bf16)c.w;
    } else {
#pragma unroll
      for (int j = 0; j < 8; ++j) v[j] = (__bf16)0.f;
    }
    *(bf16x8*)(xb + e) = v;
    return;
  }
  const float* in;
  __bf16* outp;
  int C, bx, by;
  if (b < CVT_BLOCKS + TQKV_BLOCKS) {
    int idx = b - CVT_BLOCKS;
    bx = idx % TQKV_BX; by = idx / TQKV_BX;
    in = w_qkv; outp = wqkvT; C = QKV3;
  } else {
    int idx = b - CVT_BLOCKS - TQKV_BLOCKS;
    bx = idx % TOUT_BX; by = idx / TOUT_BX;
    in = w_out; outp = woutT; C = DIM;
  }
  const int R = DIM;
  const int c0 = bx * 64, r0 = by * 64;
  const int tx = tid & 63, ty = tid >> 6;
#pragma unroll
  for (int i = 0; i < 16; ++i) {
    int r = ty * 16 + i;
    tile[r][tx] = in[(size_t)(r0 + r) * C + c0 + tx];
  }
  __syncthreads();
  const int l16 = tid & 15, cq = tid >> 4;   // l16 -> r-quad, cq -> out row (4 passes)
#pragma unroll
  for (int p = 0; p < 4; ++p) {
    int c = cq + p * 16;
    bf16x4 wv;
#pragma unroll
    for (int j = 0; j < 4; ++j) wv[j] = (__bf16)tile[l16 * 4 + j][c];
    *(bf16x4*)&outp[(size_t)(c0 + c) * R + r0 + l16 * 4] = wv;
  }
}

// ---------------- qkv GEMM: C[M][2304] = xb[M][768] * wqkvT[2304][768]^T ----------------
// 64x128 tile, 1D grid 1188 with XCD m-band swizzle, 4 waves 2x2, BK=64,
// dbuf + prefetch-first, T2 swizzle via inverse-swizzled global source col.
__global__ __launch_bounds__(256) void gemm_qkv_kernel(const __bf16* __restrict__ A,
                                                       const __bf16* __restrict__ Bt,
                                                       __bf16* __restrict__ C) {
  __shared__ __bf16 sA[2][64 * BKS];
  __shared__ __bf16 sB[2][128 * BKS];
  const int wg = xcd_swz(blockIdx.x, (MP / 64) * (QKV3 / 128));  // by-major: chunk = A-band
  const int by = wg / (QKV3 / 128), bx = wg % (QKV3 / 128);
  const int tid = threadIdx.x;
  const int w = tid >> 6, lane = tid & 63;
  const int m0 = by * 64, n0 = bx * 128;
  const int wr = w >> 1, wc = w & 1;
  const int K = DIM;
  f32x4 acc[2][4] = {};

  const int srow = (w << 3) + (lane >> 3);                 // 0..31; +it*32 keeps row&7
  const int scolE = ((lane & 7) ^ (lane >> 3)) << 3;       // inverse-swizzled source col
  const __bf16* gA = A + (size_t)(m0 + srow) * K + scolE;
  const __bf16* gB = Bt + (size_t)(n0 + srow) * K + scolE;
  const int nk = K / BKS;  // 12

#define STAGE_Q(buf, kt)                                                                 \
  do {                                                                                   \
    _Pragma("unroll")                                                                    \
    for (int it = 0; it < 2; ++it) {                                                     \
      __builtin_amdgcn_global_load_lds(                                                  \
          (const __attribute__((address_space(1))) void*)(gA + (size_t)(it * 32) * K + (kt)), \
          (__attribute__((address_space(3))) void*)(&sA[buf][(it << 11) + (w << 9)]), 16, 0, 0); \
    }                                                                                    \
    _Pragma("unroll")                                                                    \
    for (int it = 0; it < 4; ++it) {                                                     \
      __builtin_amdgcn_global_load_lds(                                                  \
          (const __attribute__((address_space(1))) void*)(gB + (size_t)(it * 32) * K + (kt)), \
          (__attribute__((address_space(3))) void*)(&sB[buf][(it << 11) + (w << 9)]), 16, 0, 0); \
    }                                                                                    \
  } while (0)

  STAGE_Q(0, 0);
  __syncthreads();

  const int sw0 = ((lane >> 4) ^ (lane & 7)) << 3;   // kk=0 swizzled slot
  const int sw1 = sw0 ^ 32;                          // kk=32
  const int rofA = (wr * 32 + (lane & 15)) * BKS;
  const int rofB = (wc * 64 + (lane & 15)) * BKS;

  for (int t = 0; t < nk; ++t) {
    const int cur = t & 1;
    if (t + 1 < nk) STAGE_Q(cur ^ 1, (t + 1) * BKS);  // issue next-tile loads first
    const __bf16* bufA = sA[cur];
    const __bf16* bufB = sB[cur];
#pragma unroll
    for (int kk = 0; kk < BKS; kk += 32) {
      const int so = (kk == 0) ? sw0 : sw1;
      bf16x8 af[2], bfr[4];
#pragma unroll
      for (int m = 0; m < 2; ++m)
        af[m] = *(const bf16x8*)&bufA[rofA + m * 16 * BKS + so];
#pragma unroll
      for (int n = 0; n < 4; ++n)
        bfr[n] = *(const bf16x8*)&bufB[rofB + n * 16 * BKS + so];
#pragma unroll
      for (int m = 0; m < 2; ++m)
#pragma unroll
        for (int n = 0; n < 4; ++n)
          acc[m][n] = __builtin_amdgcn_mfma_f32_16x16x32_bf16(af[m], bfr[n], acc[m][n], 0, 0, 0);
    }
    __syncthreads();
  }
#undef STAGE_Q

#pragma unroll
  for (int m = 0; m < 2; ++m) {
#pragma unroll
    for (int n = 0; n < 4; ++n) {
      int col = n0 + wc * 64 + n * 16 + (lane & 15);
      int rbase = m0 + wr * 32 + m * 16 + ((lane >> 4) << 2);
#pragma unroll
      for (int r = 0; r < 4; ++r) {
        C[(size_t)(rbase + r) * QKV3 + col] = (__bf16)acc[m][n][r];
      }
    }
  }
}

// ---------------- out GEMM: out[M][768] = attnb[M][768]*woutT[768][768]^T + bias ----------------
// 64x64 tile, 1D grid 792 with XCD m-band swizzle, 4 waves 2x2, BK=64, dbuf, swizzle.
__global__ __launch_bounds__(256) void gemm_out_kernel(const __bf16* __restrict__ A,
                                                       const __bf16* __restrict__ Bt,
                                                       float* __restrict__ Cv,
                                                       const float* __restrict__ bias) {
  __shared__ __bf16 sA[2][64 * BKS];
  __shared__ __bf16 sB[2][64 * BKS];
  const int wg = xcd_swz(blockIdx.x, (MP / 64) * (DIM / 64));
  const int by = wg / (DIM / 64), bx = wg % (DIM / 64);
  const int tid = threadIdx.x;
  const int w = tid >> 6, lane = tid & 63;
  const int m0 = by * 64, n0 = bx * 64;
  const int wr = w >> 1, wc = w & 1;
  const int K = DIM, N = DIM;
  f32x4 acc[2][2] = {};

  const int srow = (w << 3) + (lane >> 3);
  const int scol = ((lane & 7) ^ (lane >> 3)) << 3;
  const __bf16* gA = A + (size_t)(m0 + srow) * K + scol;
  const __bf16* gB = Bt + (size_t)(n0 + srow) * K + scol;
  const int nk = K / BKS;

#define STAGE_O(buf, kt)                                                                 \
  do {                                                                                   \
    _Pragma("unroll")                                                                    \
    for (int it = 0; it < 2; ++it) {                                                     \
      __builtin_amdgcn_global_load_lds(                                                  \
          (const __attribute__((address_space(1))) void*)(gA + (size_t)(it * 32) * K + (kt)), \
          (__attribute__((address_space(3))) void*)(&sA[buf][(it << 11) + (w << 9)]), 16, 0, 0); \
      __builtin_amdgcn_global_load_lds(                                                  \
          (const __attribute__((address_space(1))) void*)(gB + (size_t)(it * 32) * K + (kt)), \
          (__attribute__((address_space(3))) void*)(&sB[buf][(it << 11) + (w << 9)]), 16, 0, 0); \
    }                                                                                    \
  } while (0)

  STAGE_O(0, 0);
  __syncthreads();

  const int sw0 = ((lane >> 4) ^ (lane & 7)) << 3;
  const int sw1 = sw0 ^ 32;
  const int rofA = (wr * 32 + (lane & 15)) * BKS;
  const int rofB = (wc * 32 + (lane & 15)) * BKS;

  for (int t = 0; t < nk; ++t) {
    const int cur = t & 1;
    if (t + 1 < nk) STAGE_O(cur ^ 1, (t + 1) * BKS);
    const __bf16* bufA = sA[cur];
    const __bf16* bufB = sB[cur];
#pragma unroll
    for (int kk = 0; kk < BKS; kk += 32) {
      const int so = (kk == 0) ? sw0 : sw1;
      bf16x8 af[2], bfr[2];
#pragma unroll
      for (int m = 0; m < 2; ++m)
        af[m] = *(const bf16x8*)&bufA[rofA + m * 16 * BKS + so];
#pragma unroll
      for (int n = 0; n < 2; ++n)
        bfr[n] = *(const bf16x8*)&bufB[rofB + n * 16 * BKS + so];
#pragma unroll
      for (int m = 0; m < 2; ++m)
#pragma unroll
        for (int n = 0; n < 2; ++n)
          acc[m][n] = __builtin_amdgcn_mfma_f32_16x16x32_bf16(af[m], bfr[n], acc[m][n], 0, 0, 0);
    }
    __syncthreads();
  }
#undef STAGE_O

#pragma unroll
  for (int m = 0; m < 2; ++m) {
#pragma unroll
    for (int n = 0; n < 2; ++n) {
      int col = n0 + wc * 32 + n * 16 + (lane & 15);
      int rbase = m0 + wr * 32 + m * 16 + ((lane >> 4) << 2);
#pragma unroll
      for (int r = 0; r < 4; ++r) {
        int row = rbase + r;
        if (row < MROWS) Cv[(size_t)row * N + col] = acc[m][n][r] + bias[col];
      }
    }
  }
}

// ---------------- fused attention ----------------
// Windowed (t>=1): one wave per (b, blk, head, half-window). Lane = (query
// qi = wh*8 + (lane>>3), dim-eighth dq = lane&7 -> dims [dq*8, dq*8+8)).
// Dots finished by 3 shfl_xor within the 8-lane group. Two-pass softmax,
// no LDS, no fences (R7/R9/R10 lessons). CLS (t=0): split-K partials.
__global__ __launch_bounds__(64) void attn_fused_kernel(const __bf16* __restrict__ qkv,
                                                        __bf16* __restrict__ attnb,
                                                        float* __restrict__ part) {
  __shared__ float sp_lds[64];
  const int lane = threadIdx.x;

  if (blockIdx.x < WIN_BLOCKS) {
    int bidx = blockIdx.x;
    const int wh = bidx & 1; bidx >>= 1;
    const int h = bidx % HEADS; bidx /= HEADS;
    const int blk = bidx % 129;
    const int bb = bidx / 129;
    const int qi = wh * 8 + (lane >> 3);   // 0..15
    const int dq = lane & 7;               // dims [dq*8, dq*8+8)
    const int t0 = (blk == 0) ? 1 : 2 + 16 * (blk - 1);
    const int nt = (blk == 0) ? 1 : ((NTOK - t0) < 16 ? (NTOK - t0) : 16);
    const bool active = qi < nt;
    const int qt = t0 + (active ? qi : nt - 1);
    const size_t base = (size_t)bb * NTOK * QKV3;
    const int dbase = h * DHEAD + dq * 8;

    float q[8];
    {
      bf16x8 v = *(const bf16x8*)(qkv + base + (size_t)qt * QKV3 + dbase);
#pragma unroll
      for (int j = 0; j < 8; ++j) q[j] = (float)v[j];
    }

    float s[17];
    float mx = -3.4e38f;
#pragma unroll
    for (int j = 0; j < 17; ++j) {
      int jc = (j - 1) < (nt - 1) ? (j - 1) : (nt - 1);
      int kt = (j == 0) ? 0 : t0 + jc;
      bf16x8 v = *(const bf16x8*)(qkv + base + (size_t)kt * QKV3 + DIM + dbase);
      float dot = 0.f;
#pragma unroll
      for (int jj = 0; jj < 8; ++jj) dot = fmaf(q[jj], (float)v[jj], dot);
      dot += __shfl_xor(dot, 1, 64);   // combine the 8 dim-eighths
      dot += __shfl_xor(dot, 2, 64);
      dot += __shfl_xor(dot, 4, 64);
      s[j] = (j <= nt) ? dot * ATT_SCALE : -3.4e38f;
      mx = fmaxf(mx, s[j]);
    }
    float sum = 0.f;
#pragma unroll
    for (int j = 0; j < 17; ++j) {
      s[j] = expf(s[j] - mx);          // identical across the 8-lane group
      sum += s[j];
    }
    float inv = 1.f / sum;

    float o[8];
#pragma unroll
    for (int d = 0; d < 8; ++d) o[d] = 0.f;
#pragma unroll
    for (int j = 0; j < 17; ++j) {
      int jc = (j - 1) < (nt - 1) ? (j - 1) : (nt - 1);
      int vt = (j == 0) ? 0 : t0 + jc;
      bf16x8 v = *(const bf16x8*)(qkv + base + (size_t)vt * QKV3 + 2 * DIM + dbase);
      float p = s[j];
#pragma unroll
      for (int jj = 0; jj < 8; ++jj) o[jj] = fmaf(p, (float)v[jj], o[jj]);
    }

    if (active) {
      bf16x8 w;
#pragma unroll
      for (int j = 0; j < 8; ++j) w[j] = (__bf16)(o[j] * inv);
      *(bf16x8*)(attnb + (size_t)(bb * NTOK + qt) * DIM + dbase) = w;
    }
    return;
  }

  // ---- CLS split-K partials: 1 wave per (b, h, 64-key chunk) ----
  int bid = blockIdx.x - WIN_BLOCKS;
  const int sp = bid % NSPLIT;
  const int bh = bid / NSPLIT;
  const int h = bh % HEADS;
  const int bb = bh / HEADS;
  const size_t base = (size_t)bb * NTOK * QKV3;

  float q[64];
  {
    const __bf16* qp = qkv + base + h * DHEAD;
#pragma unroll
    for (int d0 = 0; d0 < 64; d0 += 8) {
      bf16x8 v = *(const bf16x8*)(qp + d0);
#pragma unroll
      for (int j = 0; j < 8; ++j) q[d0 + j] = (float)v[j];
    }
  }

  const int t = sp * 64 + lane;
  const bool valid = t < NTOK;
  const int tc = valid ? t : NTOK - 1;
  float dot = 0.f;
  {
    const __bf16* kp = qkv + base + (size_t)tc * QKV3 + DIM + h * DHEAD;
#pragma unroll
    for (int d0 = 0; d0 < 64; d0 += 8) {
      bf16x8 v = *(const bf16x8*)(kp + d0);
#pragma unroll
      for (int j = 0; j < 8; ++j) dot = fmaf(q[d0 + j], (float)v[j], dot);
    }
  }
  float s = valid ? dot * ATT_SCALE : -3.4e38f;

  float m = s;
#pragma unroll
  for (int off = 32; off > 0; off >>= 1) m = fmaxf(m, __shfl_xor(m, off, 64));
  float p = valid ? expf(s - m) : 0.f;
  float l = p;
#pragma unroll
  for (int off = 32; off > 0; off >>= 1) l += __shfl_xor(l, off, 64);

  sp_lds[lane] = p;
  __syncthreads();

  const int nt = (NTOK - sp * 64) < 64 ? (NTOK - sp * 64) : 64;
  float o = 0.f;
  const __bf16* vcol = qkv + base + (size_t)(sp * 64) * QKV3 + 2 * DIM + h * DHEAD + lane;
  for (int tt = 0; tt < nt; ++tt) {
    o = fmaf(sp_lds[tt], (float)vcol[(size_t)tt * QKV3], o);
  }

  float* pb = part + ((size_t)bh * NSPLIT + sp) * PSTRIDE;
  pb[lane] = o;
  if (lane == 0) { pb[64] = m; pb[65] = l; }
}

__global__ __launch_bounds__(64) void attn_cls_reduce(const float* __restrict__ part,
                                                      __bf16* __restrict__ attnb) {
  const int bh = blockIdx.x;
  const int h = bh % HEADS;
  const int bb = bh / HEADS;
  const int lane = threadIdx.x;
  const float* pb0 = part + (size_t)bh * NSPLIT * PSTRIDE;
  float M = -3.4e38f;
#pragma unroll
  for (int i = 0; i < NSPLIT; ++i) M = fmaxf(M, pb0[i * PSTRIDE + 64]);
  float L = 0.f, o = 0.f;
#pragma unroll
  for (int i = 0; i < NSPLIT; ++i) {
    float w = expf(pb0[i * PSTRIDE + 64] - M);
    L = fmaf(pb0[i * PSTRIDE + 65], w, L);
    o = fmaf(pb0[i * PSTRIDE + lane], w, o);
  }
  attnb[(size_t)(bb * NTOK) * DIM + h * DHEAD + lane] = (__bf16)(o / L);
}

// ---------------- launch ----------------
extern "C" void kernel_launch(void* const* d_in, const int* in_sizes, int n_in,
                              void* d_out, int out_size, void* d_ws, size_t ws_size,
                              hipStream_t stream) {
  const float* x = (const float*)d_in[0];
  const float* w_qkv = (const float*)d_in[1];
  const float* w_out = (const float*)d_in[2];
  const float* b_out = (const float*)d_in[3];
  float* out = (float*)d_out;

  char* ws = (char*)d_ws;
  __bf16* xb    = (__bf16*)(ws);                                   // MP*DIM      (6.49 MB)
  __bf16* wqkvT = (__bf16*)(ws + 6488064);                         // QKV3*DIM    (3.54 MB)
  __bf16* woutT = (__bf16*)(ws + 6488064 + 3538944);               // DIM*DIM     (1.18 MB)
  __bf16* qkvb  = (__bf16*)(ws + 6488064 + 3538944 + 1179648);     // MP*QKV3     (19.5 MB)
  __bf16* attnb = (__bf16*)(ws + 6488064 + 3538944 + 1179648 + 19464192); // MP*DIM (6.49 MB)
  float*  clsp  = (float*)(ws + 6488064 + 3538944 + 1179648 + 19464192 + 6488064); // 24*33*68*4 B

  prep_kernel<<<PREP_BLOCKS, 256, 0, stream>>>(x, w_qkv, w_out, xb, wqkvT, woutT);

  gemm_qkv_kernel<<<(MP / 64) * (QKV3 / 128), 256, 0, stream>>>(xb, wqkvT, qkvb);

  attn_fused_kernel<<<WIN_BLOCKS + BATCH * HEADS * NSPLIT, 64, 0, stream>>>(qkvb, attnb, clsp);
  attn_cls_reduce<<<BATCH * HEADS, 64, 0, stream>>>(clsp, attnb);

  gemm_out_kernel<<<(MP / 64) * (DIM / 64), 256, 0, stream>>>(attnb, woutT, out, b_out);
}